// Round 5
// baseline (252.419 us; speedup 1.0000x reference)
//
#include <hip/hip_runtime.h>
#include <hip/hip_bf16.h>

// ---------- types ----------
using f32x4  = __attribute__((ext_vector_type(4))) float;
using f32x16 = __attribute__((ext_vector_type(16))) float;
using bf16x8 = __attribute__((ext_vector_type(8))) short;   // 8 bf16 (4 VGPRs)
using u32x2  = __attribute__((ext_vector_type(2))) unsigned int;
using u32x4  = __attribute__((ext_vector_type(4))) unsigned int;

#define MFMA16(a, b, c) __builtin_amdgcn_mfma_f32_16x16x32_bf16((a), (b), (c), 0, 0, 0)
#define MFMA32(a, b, c) __builtin_amdgcn_mfma_f32_32x32x16_bf16((a), (b), (c), 0, 0, 0)

static __device__ __forceinline__ unsigned short f2bf(float x) {
    unsigned int u = __builtin_bit_cast(unsigned int, x);
    unsigned int r = (u + 0x7fffu + ((u >> 16) & 1u)) >> 16;
    return (unsigned short)r;
}

static __device__ __forceinline__ unsigned int cvtpk_bf16(float a, float b) {
    unsigned int r;
    asm("v_cvt_pk_bf16_f32 %0, %1, %2" : "=v"(r) : "v"(a), "v"(b));
    return r;
}

static __device__ __forceinline__ float exp2_fast(float x) {
#if __has_builtin(__builtin_amdgcn_exp2f)
    return __builtin_amdgcn_exp2f(x);
#else
    return __expf(x * 0.69314718056f);
#endif
}

static __device__ __forceinline__ void plswap(unsigned int& x, unsigned int& y, int hi) {
#if __has_builtin(__builtin_amdgcn_permlane32_swap)
    u32x2 r = __builtin_amdgcn_permlane32_swap(x, y, false, false);
    x = r[0]; y = r[1];
#else
    unsigned int xs = (unsigned int)__shfl_xor((int)x, 32);
    unsigned int ys = (unsigned int)__shfl_xor((int)y, 32);
    unsigned int nx = hi ? ys : x;
    unsigned int ny = hi ? y  : xs;
    x = nx; y = ny;
#endif
}

// ---------- geometry ----------
#define NB 4
#define DIMC 256
#define NN 2048
#define NH 8
#define DH 64
#define HID 512

// q scale: dhead^-0.5 * log2(e) so softmax runs in exp2 domain
#define QSCALE 0.18033688f

// workspace offsets (bytes)
#define OFF_XT  0u            // [4][2048][256] bf16 : 4 MiB
#define OFF_WQ  4194304u      // [1536][256]    bf16
#define OFF_WO  4980736u      // [256][512]     bf16
#define OFF_Q   5242880u      // [4][8][2048][64] bf16 (q * QSCALE)
#define OFF_K   13631488u     // [4][8][2048][64] bf16
#define OFF_V   22020096u     // [4][512][2048]   bf16 (V^T per batch)
#define OFF_AO  30408704u     // [4][2048][512]   bf16

// ---------- stage 0: x transpose->bf16 + weight convert (fused) ----------
__global__ __launch_bounds__(256) void k_prep(
    const float* __restrict__ x, const float* __restrict__ wqkv,
    const float* __restrict__ wout,
    unsigned short* __restrict__ xt, unsigned short* __restrict__ wq_b,
    unsigned short* __restrict__ wo_b)
{
    int wg = blockIdx.x + 32 * blockIdx.y + 128 * blockIdx.z;
    int tid = wg * 256 + threadIdx.x;
    if (tid < 98304) {
        float4 v = ((const float4*)wqkv)[tid];
        u32x2 pk; pk[0] = cvtpk_bf16(v.x, v.y); pk[1] = cvtpk_bf16(v.z, v.w);
        *(u32x2*)(wq_b + (size_t)tid * 4) = pk;
    } else {
        int t2 = tid - 98304;
        float4 v = ((const float4*)wout)[t2];
        u32x2 pk; pk[0] = cvtpk_bf16(v.x, v.y); pk[1] = cvtpk_bf16(v.z, v.w);
        *(u32x2*)(wo_b + (size_t)t2 * 4) = pk;
    }

    __shared__ unsigned short tile[64][65];
    int nb = blockIdx.x, cb = blockIdx.y, b = blockIdx.z;
    int t = threadIdx.x;
    int tn = t & 63, tg = t >> 6;
    const float* xp = x + ((size_t)(b * DIMC + cb * 64)) * NN + nb * 64;
#pragma unroll
    for (int it = 0; it < 16; ++it) {
        int c = tg * 16 + it;
        tile[c][tn] = f2bf(xp[(size_t)c * NN + tn]);
    }
    __syncthreads();
    unsigned short* op = xt + ((size_t)(b * NN + nb * 64)) * DIMC + cb * 64;
#pragma unroll
    for (int it = 0; it < 16; ++it) {
        int n = tg * 16 + it;
        op[(size_t)n * DIMC + tn] = tile[tn][n];
    }
}

// ---------- stage 1: qkv = w_qkv @ x ----------
__global__ __launch_bounds__(256) void k_qkv(
    const unsigned short* __restrict__ wq,  // [1536][256]
    const unsigned short* __restrict__ xt,  // [4][2048][256]
    unsigned short* __restrict__ qT, unsigned short* __restrict__ kT,
    unsigned short* __restrict__ vW)
{
    int bx = blockIdx.x;          // o-tile 0..23
    int nb = blockIdx.y;          // n-tile 0..31
    int b  = blockIdx.z;
    int wid = threadIdx.x >> 6;
    int l = threadIdx.x & 63, l15 = l & 15, l4 = l >> 4;
    int o0 = bx * 64, n0 = nb * 64;
    int wr = wid >> 1, wc = wid & 1;
    f32x4 acc[2][2] = {};

    if (bx < 16) {
        const unsigned short* arow = xt + ((size_t)(b * NN + n0 + wr * 32)) * DIMC;
        const unsigned short* brow = wq + (size_t)(o0 + wc * 32) * DIMC;
#pragma unroll
        for (int k0 = 0; k0 < DIMC; k0 += 32) {
            int koff = k0 + l4 * 8;
            bf16x8 a0 = *(const bf16x8*)(arow + (size_t)l15 * DIMC + koff);
            bf16x8 a1 = *(const bf16x8*)(arow + (size_t)(l15 + 16) * DIMC + koff);
            bf16x8 b0 = *(const bf16x8*)(brow + (size_t)l15 * DIMC + koff);
            bf16x8 b1 = *(const bf16x8*)(brow + (size_t)(l15 + 16) * DIMC + koff);
            acc[0][0] = MFMA16(a0, b0, acc[0][0]);
            acc[0][1] = MFMA16(a0, b1, acc[0][1]);
            acc[1][0] = MFMA16(a1, b0, acc[1][0]);
            acc[1][1] = MFMA16(a1, b1, acc[1][1]);
        }
#pragma unroll
        for (int fm = 0; fm < 2; ++fm)
#pragma unroll
            for (int fn = 0; fn < 2; ++fn) {
                int ocol = o0 + wc * 32 + fn * 16 + l15;
#pragma unroll
                for (int r = 0; r < 4; ++r) {
                    int nrow = n0 + wr * 32 + fm * 16 + l4 * 4 + r;
                    float v = acc[fm][fn][r];
                    if (ocol < HID) {  // q: fold scale * log2(e)
                        int h = ocol >> 6, d = ocol & 63;
                        qT[(((size_t)(b * NH + h)) * NN + nrow) * DH + d] = f2bf(v * QSCALE);
                    } else {           // k
                        int o2 = ocol - HID;
                        kT[(((size_t)(b * NH + (o2 >> 6))) * NN + nrow) * DH + (o2 & 63)] = f2bf(v);
                    }
                }
            }
    } else {
        const unsigned short* arow = wq + (size_t)(o0 + wr * 32) * DIMC;
        const unsigned short* brow = xt + ((size_t)(b * NN + n0 + wc * 32)) * DIMC;
#pragma unroll
        for (int k0 = 0; k0 < DIMC; k0 += 32) {
            int koff = k0 + l4 * 8;
            bf16x8 a0 = *(const bf16x8*)(arow + (size_t)l15 * DIMC + koff);
            bf16x8 a1 = *(const bf16x8*)(arow + (size_t)(l15 + 16) * DIMC + koff);
            bf16x8 b0 = *(const bf16x8*)(brow + (size_t)l15 * DIMC + koff);
            bf16x8 b1 = *(const bf16x8*)(brow + (size_t)(l15 + 16) * DIMC + koff);
            acc[0][0] = MFMA16(a0, b0, acc[0][0]);
            acc[0][1] = MFMA16(a0, b1, acc[0][1]);
            acc[1][0] = MFMA16(a1, b0, acc[1][0]);
            acc[1][1] = MFMA16(a1, b1, acc[1][1]);
        }
#pragma unroll
        for (int fm = 0; fm < 2; ++fm)
#pragma unroll
            for (int fn = 0; fn < 2; ++fn)
#pragma unroll
                for (int r = 0; r < 4; ++r) {
                    int orow = o0 + wr * 32 + fm * 16 + l4 * 4 + r;
                    int ncol = n0 + wc * 32 + fn * 16 + l15;
                    vW[((size_t)(b * HID + orow - 1024)) * NN + ncol] = f2bf(acc[fm][fn][r]);
                }
    }
}

// ---------- stage 2: flash attention, swapped 32x32x16, j-split x2 ----------
// 1024 blocks x 4 waves. wid&1 = i-subtile (32 rows), wid>>1 = KV half (1024 each).
// Doubles waves/CU (8->16) to hide the latency-bound serial chain. End combine via LDS.
__global__ __launch_bounds__(256) void k_attn4(
    const unsigned short* __restrict__ qT, const unsigned short* __restrict__ kT,
    const unsigned short* __restrict__ vW, unsigned short* __restrict__ ao)
{
    __shared__ float obuf[2][64][32];        // 16 KB: j-half-1 deposits O^T
    __shared__ float mlbuf[2][4][32];        // m, l per wave
    __shared__ unsigned short tb[2][32 * 72];// epilogue transpose (waves jw==0)

    int wg = blockIdx.x;            // 0..1023
    int xcd = wg & 7;
    int idx = wg >> 3;              // 0..127
    int bh  = xcd * 4 + (idx & 3);  // 4 bh per XCD -> K/V L2-resident
    int ib  = idx >> 2;             // 0..31
    int b = bh >> 3, h = bh & 7;
    int wid = threadIdx.x >> 6;     // 0..3
    int iw = wid & 1, jw = wid >> 1;
    int l = threadIdx.x & 63, li = l & 31, hi = l >> 5;
    int i0 = ib * 64 + iw * 32;

    const unsigned short* qb = qT + ((size_t)bh * NN) * DH;
    const unsigned short* kb = kT + ((size_t)bh * NN) * DH;
    const unsigned short* vb = vW + ((size_t)bh * DH) * NN;

    bf16x8 qf[4];
#pragma unroll
    for (int ks = 0; ks < 4; ++ks)
        qf[ks] = *(const bf16x8*)(qb + (size_t)(i0 + li) * DH + ks * 16 + hi * 8);

    f32x16 o0 = {}, o1 = {};
    float m = -1e30f, lsum = 0.f;

    const int jt0 = jw * 32, jt1 = jt0 + 32;   // 32 j-tiles of 32 = 1024 KV positions

    bf16x8 kf[4];
#pragma unroll
    for (int ks = 0; ks < 4; ++ks)
        kf[ks] = *(const bf16x8*)(kb + (size_t)(jt0 * 32 + li) * DH + ks * 16 + hi * 8);

    for (int jt = jt0; jt < jt1; ++jt) {
        int j0 = jt * 32;
        bf16x8 vf[2][2];
#pragma unroll
        for (int dt = 0; dt < 2; ++dt)
#pragma unroll
            for (int js = 0; js < 2; ++js)
                vf[dt][js] = *(const bf16x8*)(vb + (size_t)(dt * 32 + li) * NN + j0 + js * 16 + hi * 8);

        f32x16 s = {};
        __builtin_amdgcn_s_setprio(1);
        s = MFMA32(kf[0], qf[0], s);
        s = MFMA32(kf[1], qf[1], s);
        s = MFMA32(kf[2], qf[2], s);
        s = MFMA32(kf[3], qf[3], s);
        __builtin_amdgcn_s_setprio(0);

        if (jt + 1 < jt1) {
#pragma unroll
            for (int ks = 0; ks < 4; ++ks)
                kf[ks] = *(const bf16x8*)(kb + (size_t)(j0 + 32 + li) * DH + ks * 16 + hi * 8);
        }

        float t8[8];
#pragma unroll
        for (int q = 0; q < 8; ++q) t8[q] = fmaxf(s[2 * q], s[2 * q + 1]);
        float t4a = fmaxf(t8[0], t8[1]), t4b = fmaxf(t8[2], t8[3]);
        float t4c = fmaxf(t8[4], t8[5]), t4d = fmaxf(t8[6], t8[7]);
        float pmax = fmaxf(fmaxf(t4a, t4b), fmaxf(t4c, t4d));
        {
            unsigned int pu = __builtin_bit_cast(unsigned int, pmax), pv = pu;
            plswap(pu, pv, hi);
            pmax = fmaxf(__builtin_bit_cast(float, pu), __builtin_bit_cast(float, pv));
        }

        // defer-max (exp2 domain, THR=8 -> P <= 256)
        if (!__all(pmax - m <= 8.0f)) {
            float mn = fmaxf(m, pmax);
            float alpha = exp2_fast(m - mn);
            m = mn;
            lsum *= alpha;
#pragma unroll
            for (int r = 0; r < 16; ++r) { o0[r] *= alpha; o1[r] *= alpha; }
        }

        float p[16];
#pragma unroll
        for (int r = 0; r < 16; ++r) p[r] = exp2_fast(s[r] - m);
        float u8[8];
#pragma unroll
        for (int q = 0; q < 8; ++q) u8[q] = p[2 * q] + p[2 * q + 1];
        float u4a = u8[0] + u8[1], u4b = u8[2] + u8[3], u4c = u8[4] + u8[5], u4d = u8[6] + u8[7];
        float rsum = (u4a + u4b) + (u4c + u4d);
        {
            unsigned int pu = __builtin_bit_cast(unsigned int, rsum), pv = pu;
            plswap(pu, pv, hi);
            rsum = __builtin_bit_cast(float, pu) + __builtin_bit_cast(float, pv);
        }
        lsum += rsum;

        unsigned int W[8];
#pragma unroll
        for (int q = 0; q < 8; ++q) W[q] = cvtpk_bf16(p[2 * q], p[2 * q + 1]);
        plswap(W[0], W[2], hi); plswap(W[1], W[3], hi);
        plswap(W[4], W[6], hi); plswap(W[5], W[7], hi);
        u32x4 c0; c0[0] = W[0]; c0[1] = W[1]; c0[2] = W[2]; c0[3] = W[3];
        u32x4 c1; c1[0] = W[4]; c1[1] = W[5]; c1[2] = W[6]; c1[3] = W[7];
        bf16x8 pb0 = __builtin_bit_cast(bf16x8, c0);
        bf16x8 pb1 = __builtin_bit_cast(bf16x8, c1);

        __builtin_amdgcn_s_setprio(1);
        o0 = MFMA32(vf[0][0], pb0, o0);
        o0 = MFMA32(vf[0][1], pb1, o0);
        o1 = MFMA32(vf[1][0], pb0, o1);
        o1 = MFMA32(vf[1][1], pb1, o1);
        __builtin_amdgcn_s_setprio(0);
    }

    // ---- combine the two j-halves (partner wave = wid^2) ----
    mlbuf[0][wid][li] = m;
    mlbuf[1][wid][li] = lsum;
    __syncthreads();
    float mp = mlbuf[0][wid ^ 2][li];
    float lp = mlbuf[1][wid ^ 2][li];
    float mfin = fmaxf(m, mp);
    float aown = exp2_fast(m - mfin);
    float lfin = lsum * aown + lp * exp2_fast(mp - mfin);
#pragma unroll
    for (int r = 0; r < 16; ++r) { o0[r] *= aown; o1[r] *= aown; }

    if (jw == 1) {
        float* ob = &obuf[iw][0][0];
#pragma unroll
        for (int r = 0; r < 16; ++r) {
            int d0a = (r & 3) + 8 * (r >> 2) + 4 * hi;
            ob[d0a * 32 + li]        = o0[r];
            ob[(32 + d0a) * 32 + li] = o1[r];
        }
    }
    __syncthreads();
    if (jw == 0) {
        const float* ob = &obuf[iw][0][0];
#pragma unroll
        for (int r = 0; r < 16; ++r) {
            int d0a = (r & 3) + 8 * (r >> 2) + 4 * hi;
            o0[r] += ob[d0a * 32 + li];
            o1[r] += ob[(32 + d0a) * 32 + li];
        }

        float inv = 1.0f / lfin;
        unsigned short* tw = &tb[iw][0];
#pragma unroll
        for (int dt = 0; dt < 2; ++dt) {
            const f32x16& oo = dt ? o1 : o0;
#pragma unroll
            for (int q = 0; q < 8; ++q) {
                int r = 2 * q;
                int d0 = dt * 32 + (r & 3) + 8 * (r >> 2) + 4 * hi;
                unsigned int wpk = cvtpk_bf16(oo[r] * inv, oo[r + 1] * inv);
                *(unsigned int*)((char*)tw + li * 144 + d0 * 2) = wpk;
            }
        }
        __builtin_amdgcn_s_barrier();   // waves 0,1 both reach; waves 2,3 exited区? keep wave-local:
        // NOTE: tb is per-iw private; only this wave writes/reads it. The barrier above is
        // unnecessary for correctness within a wave; ds ordering within a wave is program-order.
        unsigned short* aop = ao + ((size_t)b * NN + i0 + li) * HID + h * DH + hi * 32;
#pragma unroll
        for (int k = 0; k < 4; ++k) {
            bf16x8 v = *(const bf16x8*)((const char*)tw + li * 144 + (hi * 32 + k * 8) * 2);
            *(bf16x8*)(aop + k * 8) = v;
        }
    }
}

// ---------- stage 3: out = w_out @ att + b_out ----------
__global__ __launch_bounds__(256) void k_proj(
    const unsigned short* __restrict__ wo,  // [256][512]
    const unsigned short* __restrict__ ao,  // [4][2048][512]
    const float* __restrict__ bout, float* __restrict__ out)
{
    int ob = blockIdx.x, nb = blockIdx.y, b = blockIdx.z;
    int wid = threadIdx.x >> 6;
    int l = threadIdx.x & 63, l15 = l & 15, l4 = l >> 4;
    int wr = wid >> 1, wc = wid & 1;
    int o0 = ob * 64 + wr * 32, n0 = nb * 64 + wc * 32;
    const unsigned short* arow = wo + (size_t)o0 * HID;
    const unsigned short* brow = ao + ((size_t)(b * NN) + n0) * HID;
    f32x4 acc[2][2] = {};
#pragma unroll
    for (int k0 = 0; k0 < HID; k0 += 32) {
        int koff = k0 + l4 * 8;
        bf16x8 a0 = *(const bf16x8*)(arow + (size_t)l15 * HID + koff);
        bf16x8 a1 = *(const bf16x8*)(arow + (size_t)(l15 + 16) * HID + koff);
        bf16x8 b0 = *(const bf16x8*)(brow + (size_t)l15 * HID + koff);
        bf16x8 b1 = *(const bf16x8*)(brow + (size_t)(l15 + 16) * HID + koff);
        acc[0][0] = MFMA16(a0, b0, acc[0][0]);
        acc[0][1] = MFMA16(a0, b1, acc[0][1]);
        acc[1][0] = MFMA16(a1, b0, acc[1][0]);
        acc[1][1] = MFMA16(a1, b1, acc[1][1]);
    }
#pragma unroll
    for (int fm = 0; fm < 2; ++fm)
#pragma unroll
        for (int fn = 0; fn < 2; ++fn)
#pragma unroll
            for (int r = 0; r < 4; ++r) {
                int o = o0 + fm * 16 + l4 * 4 + r;
                int n = n0 + fn * 16 + l15;
                out[((size_t)(b * DIMC + o)) * NN + n] = acc[fm][fn][r] + bout[o];
            }
}

// ---------- launch ----------
extern "C" void kernel_launch(void* const* d_in, const int* in_sizes, int n_in,
                              void* d_out, int out_size, void* d_ws, size_t ws_size,
                              hipStream_t stream)
{
    const float* x    = (const float*)d_in[0];
    const float* wqkv = (const float*)d_in[1];
    const float* wout = (const float*)d_in[2];
    const float* bout = (const float*)d_in[3];
    float* out = (float*)d_out;
    char* ws = (char*)d_ws;

    unsigned short* xt  = (unsigned short*)(ws + OFF_XT);
    unsigned short* wqb = (unsigned short*)(ws + OFF_WQ);
    unsigned short* wob = (unsigned short*)(ws + OFF_WO);
    unsigned short* qT  = (unsigned short*)(ws + OFF_Q);
    unsigned short* kT  = (unsigned short*)(ws + OFF_K);
    unsigned short* vW  = (unsigned short*)(ws + OFF_V);
    unsigned short* ao  = (unsigned short*)(ws + OFF_AO);

    hipLaunchKernelGGL(k_prep, dim3(32, 4, 4), dim3(256), 0, stream, x, wqkv, wout, xt, wqb, wob);
    hipLaunchKernelGGL(k_qkv, dim3(24, 32, 4), dim3(256), 0, stream, wqb, xt, qT, kT, vW);
    hipLaunchKernelGGL(k_attn4, dim3(1024), dim3(256), 0, stream, qT, kT, vW, ao);
    hipLaunchKernelGGL(k_proj, dim3(4, 32, 4), dim3(256), 0, stream, wob, ao, bout, out);
}

// Round 8
// 184.381 us; speedup vs baseline: 1.3690x; 1.3690x over previous
//
#include <hip/hip_runtime.h>
#include <hip/hip_bf16.h>

// ---------- types ----------
using f32x4  = __attribute__((ext_vector_type(4))) float;
using f32x16 = __attribute__((ext_vector_type(16))) float;
using bf16x8 = __attribute__((ext_vector_type(8))) short;   // 8 bf16 (4 VGPRs)
using u32x2  = __attribute__((ext_vector_type(2))) unsigned int;
using u32x4  = __attribute__((ext_vector_type(4))) unsigned int;

#define MFMA16(a, b, c) __builtin_amdgcn_mfma_f32_16x16x32_bf16((a), (b), (c), 0, 0, 0)
#define MFMA32(a, b, c) __builtin_amdgcn_mfma_f32_32x32x16_bf16((a), (b), (c), 0, 0, 0)

static __device__ __forceinline__ unsigned short f2bf(float x) {
    unsigned int u = __builtin_bit_cast(unsigned int, x);
    unsigned int r = (u + 0x7fffu + ((u >> 16) & 1u)) >> 16;
    return (unsigned short)r;
}

static __device__ __forceinline__ unsigned int cvtpk_bf16(float a, float b) {
    unsigned int r;
    asm("v_cvt_pk_bf16_f32 %0, %1, %2" : "=v"(r) : "v"(a), "v"(b));
    return r;
}

static __device__ __forceinline__ float exp2_fast(float x) {
#if __has_builtin(__builtin_amdgcn_exp2f)
    return __builtin_amdgcn_exp2f(x);
#else
    return __expf(x * 0.69314718056f);
#endif
}

static __device__ __forceinline__ void plswap(unsigned int& x, unsigned int& y, int hi) {
#if __has_builtin(__builtin_amdgcn_permlane32_swap)
    u32x2 r = __builtin_amdgcn_permlane32_swap(x, y, false, false);
    x = r[0]; y = r[1];
#else
    unsigned int xs = (unsigned int)__shfl_xor((int)x, 32);
    unsigned int ys = (unsigned int)__shfl_xor((int)y, 32);
    unsigned int nx = hi ? ys : x;
    unsigned int ny = hi ? y  : xs;
    x = nx; y = ny;
#endif
}

// ---------- geometry ----------
#define NB 4
#define DIMC 256
#define NN 2048
#define NH 8
#define DH 64
#define HID 512

// q scale: dhead^-0.5 * log2(e) so softmax runs in exp2 domain
#define QSCALE 0.18033688f

// workspace offsets (bytes)
#define OFF_XT  0u            // [4][2048][256] bf16 : 4 MiB
#define OFF_WQ  4194304u      // [1536][256]    bf16
#define OFF_WO  4980736u      // [256][512]     bf16
#define OFF_Q   5242880u      // [4][8][2048][64] bf16 (q * QSCALE, row-major [n][d])
#define OFF_K   13631488u     // [32 bh][64 jt][2048] bf16 PACKED K tiles: [ks][hi][li][8]
#define OFF_V   22020096u     // [32 bh][64 jt][2048] bf16 PACKED V^T tiles: [dt*2+js][hi][li][8]
#define OFF_AO  30408704u     // [4][2048][512]   bf16

// ---------- stage 0: x transpose->bf16 + weight convert (fused) ----------
__global__ __launch_bounds__(256) void k_prep(
    const float* __restrict__ x, const float* __restrict__ wqkv,
    const float* __restrict__ wout,
    unsigned short* __restrict__ xt, unsigned short* __restrict__ wq_b,
    unsigned short* __restrict__ wo_b)
{
    int wg = blockIdx.x + 32 * blockIdx.y + 128 * blockIdx.z;
    int tid = wg * 256 + threadIdx.x;
    if (tid < 98304) {
        float4 v = ((const float4*)wqkv)[tid];
        u32x2 pk; pk[0] = cvtpk_bf16(v.x, v.y); pk[1] = cvtpk_bf16(v.z, v.w);
        *(u32x2*)(wq_b + (size_t)tid * 4) = pk;
    } else {
        int t2 = tid - 98304;
        float4 v = ((const float4*)wout)[t2];
        u32x2 pk; pk[0] = cvtpk_bf16(v.x, v.y); pk[1] = cvtpk_bf16(v.z, v.w);
        *(u32x2*)(wo_b + (size_t)t2 * 4) = pk;
    }

    __shared__ unsigned short tile[64][65];
    int nb = blockIdx.x, cb = blockIdx.y, b = blockIdx.z;
    int t = threadIdx.x;
    int tn = t & 63, tg = t >> 6;
    const float* xp = x + ((size_t)(b * DIMC + cb * 64)) * NN + nb * 64;
#pragma unroll
    for (int it = 0; it < 16; ++it) {
        int c = tg * 16 + it;
        tile[c][tn] = f2bf(xp[(size_t)c * NN + tn]);
    }
    __syncthreads();
    unsigned short* op = xt + ((size_t)(b * NN + nb * 64)) * DIMC + cb * 64;
#pragma unroll
    for (int it = 0; it < 16; ++it) {
        int n = tg * 16 + it;
        op[(size_t)n * DIMC + tn] = tile[tn][n];
    }
}

// ---------- stage 1: qkv = w_qkv @ x ----------
// K/V epilogues write MFMA-fragment-packed tile layouts so k_attn loads are
// fully coalesced (1 KB/wave-instr) instead of 128B-strided gathers.
__global__ __launch_bounds__(256) void k_qkv(
    const unsigned short* __restrict__ wq,  // [1536][256]
    const unsigned short* __restrict__ xt,  // [4][2048][256]
    unsigned short* __restrict__ qT, unsigned short* __restrict__ kTt,
    unsigned short* __restrict__ vTt)
{
    int bx = blockIdx.x;          // o-tile 0..23
    int nb = blockIdx.y;          // n-tile 0..31
    int b  = blockIdx.z;
    int wid = threadIdx.x >> 6;
    int l = threadIdx.x & 63, l15 = l & 15, l4 = l >> 4;
    int o0 = bx * 64, n0 = nb * 64;
    int wr = wid >> 1, wc = wid & 1;
    f32x4 acc[2][2] = {};

    if (bx < 16) {
        const unsigned short* arow = xt + ((size_t)(b * NN + n0 + wr * 32)) * DIMC;
        const unsigned short* brow = wq + (size_t)(o0 + wc * 32) * DIMC;
#pragma unroll
        for (int k0 = 0; k0 < DIMC; k0 += 32) {
            int koff = k0 + l4 * 8;
            bf16x8 a0 = *(const bf16x8*)(arow + (size_t)l15 * DIMC + koff);
            bf16x8 a1 = *(const bf16x8*)(arow + (size_t)(l15 + 16) * DIMC + koff);
            bf16x8 b0 = *(const bf16x8*)(brow + (size_t)l15 * DIMC + koff);
            bf16x8 b1 = *(const bf16x8*)(brow + (size_t)(l15 + 16) * DIMC + koff);
            acc[0][0] = MFMA16(a0, b0, acc[0][0]);
            acc[0][1] = MFMA16(a0, b1, acc[0][1]);
            acc[1][0] = MFMA16(a1, b0, acc[1][0]);
            acc[1][1] = MFMA16(a1, b1, acc[1][1]);
        }
#pragma unroll
        for (int fm = 0; fm < 2; ++fm)
#pragma unroll
            for (int fn = 0; fn < 2; ++fn) {
                int ocol = o0 + wc * 32 + fn * 16 + l15;
#pragma unroll
                for (int r = 0; r < 4; ++r) {
                    int nrow = n0 + wr * 32 + fm * 16 + l4 * 4 + r;
                    float v = acc[fm][fn][r];
                    if (ocol < HID) {  // q: fold scale * log2(e); layout [bh][n][d]
                        int h = ocol >> 6, d = ocol & 63;
                        qT[(((size_t)(b * NH + h)) * NN + nrow) * DH + d] = f2bf(v * QSCALE);
                    } else {           // k -> packed tile [bh][jt][ks][hi][li][8]
                        int o2 = ocol - HID;
                        int h = o2 >> 6, d = o2 & 63;
                        int jt = nrow >> 5, li2 = nrow & 31;
                        int ks = d >> 4, hi2 = (d >> 3) & 1, e = d & 7;
                        kTt[((size_t)(b * NH + h) * 64 + jt) * 2048
                            + ks * 512 + hi2 * 256 + li2 * 8 + e] = f2bf(v);
                    }
                }
            }
    } else {
        const unsigned short* arow = wq + (size_t)(o0 + wr * 32) * DIMC;
        const unsigned short* brow = xt + ((size_t)(b * NN + n0 + wc * 32)) * DIMC;
#pragma unroll
        for (int k0 = 0; k0 < DIMC; k0 += 32) {
            int koff = k0 + l4 * 8;
            bf16x8 a0 = *(const bf16x8*)(arow + (size_t)l15 * DIMC + koff);
            bf16x8 a1 = *(const bf16x8*)(arow + (size_t)(l15 + 16) * DIMC + koff);
            bf16x8 b0 = *(const bf16x8*)(brow + (size_t)l15 * DIMC + koff);
            bf16x8 b1 = *(const bf16x8*)(brow + (size_t)(l15 + 16) * DIMC + koff);
            acc[0][0] = MFMA16(a0, b0, acc[0][0]);
            acc[0][1] = MFMA16(a0, b1, acc[0][1]);
            acc[1][0] = MFMA16(a1, b0, acc[1][0]);
            acc[1][1] = MFMA16(a1, b1, acc[1][1]);
        }
        // v -> packed tile [bh][jt][dt*2+js][hi][li][8]
#pragma unroll
        for (int fm = 0; fm < 2; ++fm)
#pragma unroll
            for (int fn = 0; fn < 2; ++fn)
#pragma unroll
                for (int r = 0; r < 4; ++r) {
                    int orow = o0 + wr * 32 + fm * 16 + l4 * 4 + r;
                    int ncol = n0 + wc * 32 + fn * 16 + l15;
                    int o2 = orow - 1024;
                    int h = o2 >> 6, dd = o2 & 63;
                    int j = ncol;
                    int jt = j >> 5, js = (j >> 4) & 1, hi2 = (j >> 3) & 1, e = j & 7;
                    int dt = dd >> 5, li2 = dd & 31;
                    vTt[((size_t)(b * NH + h) * 64 + jt) * 2048
                        + (dt * 2 + js) * 512 + hi2 * 256 + li2 * 8 + e] = f2bf(acc[fm][fn][r]);
                }
    }
}

// ---------- stage 2: flash attention, swapped 32x32x16, j-split x2, packed K/V ----------
// 1024 blocks x 4 waves. wid&1 = i-subtile (32 rows), wid>>1 = KV half (1024 each).
// All K/V loads: base + f*512 + l*8 -> coalesced 1 KB per wave-instruction.
__global__ __launch_bounds__(256) void k_attn5(
    const unsigned short* __restrict__ qT, const unsigned short* __restrict__ kTt,
    const unsigned short* __restrict__ vTt, unsigned short* __restrict__ ao)
{
    __shared__ float obuf[2][64][32];        // 16 KB: j-half-1 deposits O^T
    __shared__ float mlbuf[2][4][32];        // m, l per wave
    __shared__ unsigned short tb[2][32 * 72];// epilogue transpose (waves jw==0)

    int wg = blockIdx.x;            // 0..1023
    int xcd = wg & 7;
    int idx = wg >> 3;              // 0..127
    int bh  = xcd * 4 + (idx & 3);  // 4 bh per XCD -> K/V L2-resident
    int ib  = idx >> 2;             // 0..31
    int b = bh >> 3, h = bh & 7;
    int wid = threadIdx.x >> 6;     // 0..3
    int iw = wid & 1, jw = wid >> 1;
    int l = threadIdx.x & 63, li = l & 31, hi = l >> 5;
    int i0 = ib * 64 + iw * 32;

    const unsigned short* qb  = qT + ((size_t)bh * NN) * DH;
    const unsigned short* ktb = kTt + (size_t)bh * 64 * 2048;
    const unsigned short* vtb = vTt + (size_t)bh * 64 * 2048;

    bf16x8 qf[4];
#pragma unroll
    for (int ks = 0; ks < 4; ++ks)
        qf[ks] = *(const bf16x8*)(qb + (size_t)(i0 + li) * DH + ks * 16 + hi * 8);

    f32x16 o0 = {}, o1 = {};
    float m = -1e30f, lsum = 0.f;

    const int jt0 = jw * 32, jt1 = jt0 + 32;   // 32 j-tiles of 32 = 1024 KV positions

    const unsigned short* kcur = ktb + (size_t)jt0 * 2048;
    bf16x8 kf[4];
#pragma unroll
    for (int ks = 0; ks < 4; ++ks)
        kf[ks] = *(const bf16x8*)(kcur + ks * 512 + l * 8);

    for (int jt = jt0; jt < jt1; ++jt) {
        const unsigned short* vcur = vtb + (size_t)jt * 2048;
        bf16x8 vf[4];
#pragma unroll
        for (int f = 0; f < 4; ++f)
            vf[f] = *(const bf16x8*)(vcur + f * 512 + l * 8);

        f32x16 s = {};
        __builtin_amdgcn_s_setprio(1);
        s = MFMA32(kf[0], qf[0], s);
        s = MFMA32(kf[1], qf[1], s);
        s = MFMA32(kf[2], qf[2], s);
        s = MFMA32(kf[3], qf[3], s);
        __builtin_amdgcn_s_setprio(0);

        kcur += 2048;
        if (jt + 1 < jt1) {
#pragma unroll
            for (int ks = 0; ks < 4; ++ks)
                kf[ks] = *(const bf16x8*)(kcur + ks * 512 + l * 8);
        }

        float t8[8];
#pragma unroll
        for (int q = 0; q < 8; ++q) t8[q] = fmaxf(s[2 * q], s[2 * q + 1]);
        float t4a = fmaxf(t8[0], t8[1]), t4b = fmaxf(t8[2], t8[3]);
        float t4c = fmaxf(t8[4], t8[5]), t4d = fmaxf(t8[6], t8[7]);
        float pmax = fmaxf(fmaxf(t4a, t4b), fmaxf(t4c, t4d));
        {
            unsigned int pu = __builtin_bit_cast(unsigned int, pmax), pv = pu;
            plswap(pu, pv, hi);
            pmax = fmaxf(__builtin_bit_cast(float, pu), __builtin_bit_cast(float, pv));
        }

        // defer-max (exp2 domain, THR=8 -> P <= 256)
        if (!__all(pmax - m <= 8.0f)) {
            float mn = fmaxf(m, pmax);
            float alpha = exp2_fast(m - mn);
            m = mn;
            lsum *= alpha;
#pragma unroll
            for (int r = 0; r < 16; ++r) { o0[r] *= alpha; o1[r] *= alpha; }
        }

        float p[16];
#pragma unroll
        for (int r = 0; r < 16; ++r) p[r] = exp2_fast(s[r] - m);
        float u8[8];
#pragma unroll
        for (int q = 0; q < 8; ++q) u8[q] = p[2 * q] + p[2 * q + 1];
        float u4a = u8[0] + u8[1], u4b = u8[2] + u8[3], u4c = u8[4] + u8[5], u4d = u8[6] + u8[7];
        float rsum = (u4a + u4b) + (u4c + u4d);
        {
            unsigned int pu = __builtin_bit_cast(unsigned int, rsum), pv = pu;
            plswap(pu, pv, hi);
            rsum = __builtin_bit_cast(float, pu) + __builtin_bit_cast(float, pv);
        }
        lsum += rsum;

        unsigned int W[8];
#pragma unroll
        for (int q = 0; q < 8; ++q) W[q] = cvtpk_bf16(p[2 * q], p[2 * q + 1]);
        plswap(W[0], W[2], hi); plswap(W[1], W[3], hi);
        plswap(W[4], W[6], hi); plswap(W[5], W[7], hi);
        u32x4 c0; c0[0] = W[0]; c0[1] = W[1]; c0[2] = W[2]; c0[3] = W[3];
        u32x4 c1; c1[0] = W[4]; c1[1] = W[5]; c1[2] = W[6]; c1[3] = W[7];
        bf16x8 pb0 = __builtin_bit_cast(bf16x8, c0);
        bf16x8 pb1 = __builtin_bit_cast(bf16x8, c1);

        __builtin_amdgcn_s_setprio(1);
        o0 = MFMA32(vf[0], pb0, o0);
        o0 = MFMA32(vf[1], pb1, o0);
        o1 = MFMA32(vf[2], pb0, o1);
        o1 = MFMA32(vf[3], pb1, o1);
        __builtin_amdgcn_s_setprio(0);
    }

    // ---- combine the two j-halves (partner wave = wid^2) ----
    mlbuf[0][wid][li] = m;
    mlbuf[1][wid][li] = lsum;
    __syncthreads();
    float mp = mlbuf[0][wid ^ 2][li];
    float lp = mlbuf[1][wid ^ 2][li];
    float mfin = fmaxf(m, mp);
    float aown = exp2_fast(m - mfin);
    float lfin = lsum * aown + lp * exp2_fast(mp - mfin);
#pragma unroll
    for (int r = 0; r < 16; ++r) { o0[r] *= aown; o1[r] *= aown; }

    if (jw == 1) {
        float* ob = &obuf[iw][0][0];
#pragma unroll
        for (int r = 0; r < 16; ++r) {
            int d0a = (r & 3) + 8 * (r >> 2) + 4 * hi;
            ob[d0a * 32 + li]        = o0[r];
            ob[(32 + d0a) * 32 + li] = o1[r];
        }
    }
    __syncthreads();
    if (jw == 0) {
        const float* ob = &obuf[iw][0][0];
#pragma unroll
        for (int r = 0; r < 16; ++r) {
            int d0a = (r & 3) + 8 * (r >> 2) + 4 * hi;
            o0[r] += ob[d0a * 32 + li];
            o1[r] += ob[(32 + d0a) * 32 + li];
        }

        float inv = 1.0f / lfin;
        unsigned short* tw = &tb[iw][0];
#pragma unroll
        for (int dt = 0; dt < 2; ++dt) {
            const f32x16& oo = dt ? o1 : o0;
#pragma unroll
            for (int q = 0; q < 8; ++q) {
                int r = 2 * q;
                int d0 = dt * 32 + (r & 3) + 8 * (r >> 2) + 4 * hi;
                unsigned int wpk = cvtpk_bf16(oo[r] * inv, oo[r + 1] * inv);
                *(unsigned int*)((char*)tw + li * 144 + d0 * 2) = wpk;
            }
        }
        // tb is wave-private (iw-indexed); in-wave ds ordering is program-order.
        unsigned short* aop = ao + ((size_t)b * NN + i0 + li) * HID + h * DH + hi * 32;
#pragma unroll
        for (int k = 0; k < 4; ++k) {
            bf16x8 v = *(const bf16x8*)((const char*)tw + li * 144 + (hi * 32 + k * 8) * 2);
            *(bf16x8*)(aop + k * 8) = v;
        }
    }
}

// ---------- stage 3: out = w_out @ att + b_out ----------
__global__ __launch_bounds__(256) void k_proj(
    const unsigned short* __restrict__ wo,  // [256][512]
    const unsigned short* __restrict__ ao,  // [4][2048][512]
    const float* __restrict__ bout, float* __restrict__ out)
{
    int ob = blockIdx.x, nb = blockIdx.y, b = blockIdx.z;
    int wid = threadIdx.x >> 6;
    int l = threadIdx.x & 63, l15 = l & 15, l4 = l >> 4;
    int wr = wid >> 1, wc = wid & 1;
    int o0 = ob * 64 + wr * 32, n0 = nb * 64 + wc * 32;
    const unsigned short* arow = wo + (size_t)o0 * HID;
    const unsigned short* brow = ao + ((size_t)(b * NN) + n0) * HID;
    f32x4 acc[2][2] = {};
#pragma unroll
    for (int k0 = 0; k0 < HID; k0 += 32) {
        int koff = k0 + l4 * 8;
        bf16x8 a0 = *(const bf16x8*)(arow + (size_t)l15 * HID + koff);
        bf16x8 a1 = *(const bf16x8*)(arow + (size_t)(l15 + 16) * HID + koff);
        bf16x8 b0 = *(const bf16x8*)(brow + (size_t)l15 * HID + koff);
        bf16x8 b1 = *(const bf16x8*)(brow + (size_t)(l15 + 16) * HID + koff);
        acc[0][0] = MFMA16(a0, b0, acc[0][0]);
        acc[0][1] = MFMA16(a0, b1, acc[0][1]);
        acc[1][0] = MFMA16(a1, b0, acc[1][0]);
        acc[1][1] = MFMA16(a1, b1, acc[1][1]);
    }
#pragma unroll
    for (int fm = 0; fm < 2; ++fm)
#pragma unroll
        for (int fn = 0; fn < 2; ++fn)
#pragma unroll
            for (int r = 0; r < 4; ++r) {
                int o = o0 + fm * 16 + l4 * 4 + r;
                int n = n0 + fn * 16 + l15;
                out[((size_t)(b * DIMC + o)) * NN + n] = acc[fm][fn][r] + bout[o];
            }
}

// ---------- launch ----------
extern "C" void kernel_launch(void* const* d_in, const int* in_sizes, int n_in,
                              void* d_out, int out_size, void* d_ws, size_t ws_size,
                              hipStream_t stream)
{
    const float* x    = (const float*)d_in[0];
    const float* wqkv = (const float*)d_in[1];
    const float* wout = (const float*)d_in[2];
    const float* bout = (const float*)d_in[3];
    float* out = (float*)d_out;
    char* ws = (char*)d_ws;

    unsigned short* xt  = (unsigned short*)(ws + OFF_XT);
    unsigned short* wqb = (unsigned short*)(ws + OFF_WQ);
    unsigned short* wob = (unsigned short*)(ws + OFF_WO);
    unsigned short* qT  = (unsigned short*)(ws + OFF_Q);
    unsigned short* kTt = (unsigned short*)(ws + OFF_K);
    unsigned short* vTt = (unsigned short*)(ws + OFF_V);
    unsigned short* ao  = (unsigned short*)(ws + OFF_AO);

    hipLaunchKernelGGL(k_prep, dim3(32, 4, 4), dim3(256), 0, stream, x, wqkv, wout, xt, wqb, wob);
    hipLaunchKernelGGL(k_qkv, dim3(24, 32, 4), dim3(256), 0, stream, wqb, xt, qT, kTt, vTt);
    hipLaunchKernelGGL(k_attn5, dim3(1024), dim3(256), 0, stream, qT, kTt, vTt, ao);
    hipLaunchKernelGGL(k_proj, dim3(4, 32, 4), dim3(256), 0, stream, wob, ao, bout, out);
}

// Round 9
// 159.447 us; speedup vs baseline: 1.5831x; 1.1564x over previous
//
#include <hip/hip_runtime.h>
#include <hip/hip_bf16.h>

// ---------- types ----------
using f32x4  = __attribute__((ext_vector_type(4))) float;
using f32x16 = __attribute__((ext_vector_type(16))) float;
using bf16x8 = __attribute__((ext_vector_type(8))) short;   // 8 bf16 (4 VGPRs)
using u32x2  = __attribute__((ext_vector_type(2))) unsigned int;
using u32x4  = __attribute__((ext_vector_type(4))) unsigned int;

#define MFMA16(a, b, c) __builtin_amdgcn_mfma_f32_16x16x32_bf16((a), (b), (c), 0, 0, 0)
#define MFMA32(a, b, c) __builtin_amdgcn_mfma_f32_32x32x16_bf16((a), (b), (c), 0, 0, 0)

static __device__ __forceinline__ unsigned short f2bf(float x) {
    unsigned int u = __builtin_bit_cast(unsigned int, x);
    unsigned int r = (u + 0x7fffu + ((u >> 16) & 1u)) >> 16;
    return (unsigned short)r;
}

static __device__ __forceinline__ unsigned int cvtpk_bf16(float a, float b) {
    unsigned int r;
    asm("v_cvt_pk_bf16_f32 %0, %1, %2" : "=v"(r) : "v"(a), "v"(b));
    return r;
}

static __device__ __forceinline__ float exp2_fast(float x) {
#if __has_builtin(__builtin_amdgcn_exp2f)
    return __builtin_amdgcn_exp2f(x);
#else
    return __expf(x * 0.69314718056f);
#endif
}

static __device__ __forceinline__ void plswap(unsigned int& x, unsigned int& y, int hi) {
#if __has_builtin(__builtin_amdgcn_permlane32_swap)
    u32x2 r = __builtin_amdgcn_permlane32_swap(x, y, false, false);
    x = r[0]; y = r[1];
#else
    unsigned int xs = (unsigned int)__shfl_xor((int)x, 32);
    unsigned int ys = (unsigned int)__shfl_xor((int)y, 32);
    unsigned int nx = hi ? ys : x;
    unsigned int ny = hi ? y  : xs;
    x = nx; y = ny;
#endif
}

// ---------- geometry ----------
#define NB 4
#define DIMC 256
#define NN 2048
#define NH 8
#define DH 64
#define HID 512

// q scale: dhead^-0.5 * log2(e) so softmax runs in exp2 domain
#define QSCALE 0.18033688f

// Fragtile packed operand layout (for 16x16x32 MFMA fragment loads):
//   element (row, col) -> [rt=row/32][kt=col/32][sub=(row&31)>>4][l15=row&15][l4=(col>>3)&3][e=col&7]
//   a0/b0 = tilebase + lane_off, a1/b1 = tilebase + 512, lane_off = l15*32 + l4*8.
//   Each wave-load covers a contiguous 1 KB block.

// workspace offsets (bytes)
#define OFF_XT  0u            // [4] packed x^T  (rows n, K=256): 64rt x 8kt x 2KB = 1 MiB/batch
#define OFF_WQ  4194304u      // packed w_qkv (rows o=1536, K=256): 48rt x 8kt
#define OFF_WO  4980736u      // packed w_out (rows o=256, K=512):  8rt x 16kt
#define OFF_Q   5242880u      // [4][8][2048][64] bf16 (q * QSCALE, row-major [n][d])
#define OFF_K   13631488u     // [32 bh][64 jt][2048] bf16 PACKED K tiles: [ks][hi][li][8]
#define OFF_V   22020096u     // [32 bh][64 jt][2048] bf16 PACKED V^T tiles: [dt*2+js][hi][li][8]
#define OFF_AO  30408704u     // [4] packed attn-out (rows n, K=hid=512): 64rt x 16kt

// ---------- stage 0: x transpose->packed bf16 + weight convert->packed (fused) ----------
__global__ __launch_bounds__(256) void k_prep(
    const float* __restrict__ x, const float* __restrict__ wqkv,
    const float* __restrict__ wout,
    unsigned short* __restrict__ xt, unsigned short* __restrict__ wq_b,
    unsigned short* __restrict__ wo_b)
{
    int wg = blockIdx.x + 32 * blockIdx.y + 128 * blockIdx.z;
    int tid = wg * 256 + threadIdx.x;
    if (tid < 98304) {
        // wqkv [1536][256]: 64 float4 per row
        int o = tid >> 6, c4 = (tid & 63) * 4;
        float4 v = ((const float4*)wqkv)[tid];
        u32x2 pk; pk[0] = cvtpk_bf16(v.x, v.y); pk[1] = cvtpk_bf16(v.z, v.w);
        int rt = o >> 5, rr = o & 31, sub = rr >> 4, l15f = rr & 15;
        int kt = c4 >> 5, l4f = (c4 >> 3) & 3, e = c4 & 7;
        size_t off = (size_t)(((rt * 8 + kt) * 2 + sub)) * 512 + l15f * 32 + l4f * 8 + e;
        *(u32x2*)(wq_b + off) = pk;
    } else {
        // wout [256][512]: 128 float4 per row
        int t2 = tid - 98304;
        int o = t2 >> 7, c4 = (t2 & 127) * 4;
        float4 v = ((const float4*)wout)[t2];
        u32x2 pk; pk[0] = cvtpk_bf16(v.x, v.y); pk[1] = cvtpk_bf16(v.z, v.w);
        int rt = o >> 5, rr = o & 31, sub = rr >> 4, l15f = rr & 15;
        int kt = c4 >> 5, l4f = (c4 >> 3) & 3, e = c4 & 7;
        size_t off = (size_t)(((rt * 16 + kt) * 2 + sub)) * 512 + l15f * 32 + l4f * 8 + e;
        *(u32x2*)(wo_b + off) = pk;
    }

    __shared__ unsigned short tile[64][65];
    int nb = blockIdx.x, cb = blockIdx.y, b = blockIdx.z;
    int t = threadIdx.x;
    int tn = t & 63, tg = t >> 6;
    const float* xp = x + ((size_t)(b * DIMC + cb * 64)) * NN + nb * 64;
#pragma unroll
    for (int it = 0; it < 16; ++it) {
        int c = tg * 16 + it;
        tile[c][tn] = f2bf(xp[(size_t)c * NN + tn]);
    }
    __syncthreads();
    // packed write: row R = nb*64 + n, col C = cb*64 + tn
    unsigned short* xb = xt + (size_t)b * NN * DIMC;
    int C = cb * 64 + tn;
    int kt = C >> 5, l4f = (C >> 3) & 3, e = C & 7;
#pragma unroll
    for (int it = 0; it < 16; ++it) {
        int n = tg * 16 + it;
        int R = nb * 64 + n;
        int rt = R >> 5, rr = R & 31, sub = rr >> 4, l15f = rr & 15;
        xb[(size_t)(((rt * 8 + kt) * 2 + sub)) * 512 + l15f * 32 + l4f * 8 + e] = tile[tn][n];
    }
}

// ---------- stage 1: qkv = w_qkv @ x (packed operands) ----------
// K/V epilogues write MFMA-fragment-packed tile layouts so k_attn loads are
// fully coalesced; A/B fragment loads are lane-linear from packed xt/wq.
__global__ __launch_bounds__(256) void k_qkv(
    const unsigned short* __restrict__ wq,  // packed [48rt][8kt]
    const unsigned short* __restrict__ xt,  // packed [4][64rt][8kt]
    unsigned short* __restrict__ qT, unsigned short* __restrict__ kTt,
    unsigned short* __restrict__ vTt)
{
    int bx = blockIdx.x;          // o-tile 0..23
    int nb = blockIdx.y;          // n-tile 0..31
    int b  = blockIdx.z;
    int wid = threadIdx.x >> 6;
    int l = threadIdx.x & 63, l15 = l & 15, l4 = l >> 4;
    int o0 = bx * 64, n0 = nb * 64;
    int wr = wid >> 1, wc = wid & 1;
    int lane_off = l15 * 32 + l4 * 8;
    const unsigned short* xb = xt + (size_t)b * NN * DIMC;
    f32x4 acc[2][2] = {};

    if (bx < 16) {
        int rt_a = nb * 2 + wr;      // A = xt rows n
        int rt_b = bx * 2 + wc;      // B = wq rows o
#pragma unroll
        for (int kt = 0; kt < 8; ++kt) {
            const unsigned short* at = xb + (size_t)((rt_a * 8 + kt) * 2) * 512 + lane_off;
            const unsigned short* bt = wq + (size_t)((rt_b * 8 + kt) * 2) * 512 + lane_off;
            bf16x8 a0 = *(const bf16x8*)(at);
            bf16x8 a1 = *(const bf16x8*)(at + 512);
            bf16x8 b0 = *(const bf16x8*)(bt);
            bf16x8 b1 = *(const bf16x8*)(bt + 512);
            acc[0][0] = MFMA16(a0, b0, acc[0][0]);
            acc[0][1] = MFMA16(a0, b1, acc[0][1]);
            acc[1][0] = MFMA16(a1, b0, acc[1][0]);
            acc[1][1] = MFMA16(a1, b1, acc[1][1]);
        }
#pragma unroll
        for (int fm = 0; fm < 2; ++fm)
#pragma unroll
            for (int fn = 0; fn < 2; ++fn) {
                int ocol = o0 + wc * 32 + fn * 16 + l15;
#pragma unroll
                for (int r = 0; r < 4; ++r) {
                    int nrow = n0 + wr * 32 + fm * 16 + l4 * 4 + r;
                    float v = acc[fm][fn][r];
                    if (ocol < HID) {  // q: fold scale * log2(e); layout [bh][n][d]
                        int h = ocol >> 6, d = ocol & 63;
                        qT[(((size_t)(b * NH + h)) * NN + nrow) * DH + d] = f2bf(v * QSCALE);
                    } else {           // k -> packed tile [bh][jt][ks][hi][li][8]
                        int o2 = ocol - HID;
                        int h = o2 >> 6, d = o2 & 63;
                        int jt = nrow >> 5, li2 = nrow & 31;
                        int ks = d >> 4, hi2 = (d >> 3) & 1, e = d & 7;
                        kTt[((size_t)(b * NH + h) * 64 + jt) * 2048
                            + ks * 512 + hi2 * 256 + li2 * 8 + e] = f2bf(v);
                    }
                }
            }
    } else {
        int rt_a = bx * 2 + wr;      // A = wq rows o (1024..1535)
        int rt_b = nb * 2 + wc;      // B = xt rows n
#pragma unroll
        for (int kt = 0; kt < 8; ++kt) {
            const unsigned short* at = wq + (size_t)((rt_a * 8 + kt) * 2) * 512 + lane_off;
            const unsigned short* bt = xb + (size_t)((rt_b * 8 + kt) * 2) * 512 + lane_off;
            bf16x8 a0 = *(const bf16x8*)(at);
            bf16x8 a1 = *(const bf16x8*)(at + 512);
            bf16x8 b0 = *(const bf16x8*)(bt);
            bf16x8 b1 = *(const bf16x8*)(bt + 512);
            acc[0][0] = MFMA16(a0, b0, acc[0][0]);
            acc[0][1] = MFMA16(a0, b1, acc[0][1]);
            acc[1][0] = MFMA16(a1, b0, acc[1][0]);
            acc[1][1] = MFMA16(a1, b1, acc[1][1]);
        }
        // v -> packed tile [bh][jt][dt*2+js][hi][li][8]
#pragma unroll
        for (int fm = 0; fm < 2; ++fm)
#pragma unroll
            for (int fn = 0; fn < 2; ++fn)
#pragma unroll
                for (int r = 0; r < 4; ++r) {
                    int orow = o0 + wr * 32 + fm * 16 + l4 * 4 + r;
                    int ncol = n0 + wc * 32 + fn * 16 + l15;
                    int o2 = orow - 1024;
                    int h = o2 >> 6, dd = o2 & 63;
                    int j = ncol;
                    int jt = j >> 5, js = (j >> 4) & 1, hi2 = (j >> 3) & 1, e = j & 7;
                    int dt = dd >> 5, li2 = dd & 31;
                    vTt[((size_t)(b * NH + h) * 64 + jt) * 2048
                        + (dt * 2 + js) * 512 + hi2 * 256 + li2 * 8 + e] = f2bf(acc[fm][fn][r]);
                }
    }
}

// ---------- stage 2: flash attention, swapped 32x32x16, j-split x2, packed K/V ----------
// 1024 blocks x 4 waves. wid&1 = i-subtile (32 rows), wid>>1 = KV half (1024 each).
// All K/V loads coalesced; ao written in fragtile-packed layout for k_proj.
__global__ __launch_bounds__(256) void k_attn5(
    const unsigned short* __restrict__ qT, const unsigned short* __restrict__ kTt,
    const unsigned short* __restrict__ vTt, unsigned short* __restrict__ ao)
{
    __shared__ float obuf[2][64][32];        // 16 KB: j-half-1 deposits O^T
    __shared__ float mlbuf[2][4][32];        // m, l per wave
    __shared__ unsigned short tb[2][32 * 72];// epilogue transpose (waves jw==0)

    int wg = blockIdx.x;            // 0..1023
    int xcd = wg & 7;
    int idx = wg >> 3;              // 0..127
    int bh  = xcd * 4 + (idx & 3);  // 4 bh per XCD -> K/V L2-resident
    int ib  = idx >> 2;             // 0..31
    int b = bh >> 3, h = bh & 7;
    int wid = threadIdx.x >> 6;     // 0..3
    int iw = wid & 1, jw = wid >> 1;
    int l = threadIdx.x & 63, li = l & 31, hi = l >> 5;
    int i0 = ib * 64 + iw * 32;

    const unsigned short* qb  = qT + ((size_t)bh * NN) * DH;
    const unsigned short* ktb = kTt + (size_t)bh * 64 * 2048;
    const unsigned short* vtb = vTt + (size_t)bh * 64 * 2048;

    bf16x8 qf[4];
#pragma unroll
    for (int ks = 0; ks < 4; ++ks)
        qf[ks] = *(const bf16x8*)(qb + (size_t)(i0 + li) * DH + ks * 16 + hi * 8);

    f32x16 o0 = {}, o1 = {};
    float m = -1e30f, lsum = 0.f;

    const int jt0 = jw * 32, jt1 = jt0 + 32;   // 32 j-tiles of 32 = 1024 KV positions

    const unsigned short* kcur = ktb + (size_t)jt0 * 2048;
    bf16x8 kf[4];
#pragma unroll
    for (int ks = 0; ks < 4; ++ks)
        kf[ks] = *(const bf16x8*)(kcur + ks * 512 + l * 8);

    for (int jt = jt0; jt < jt1; ++jt) {
        const unsigned short* vcur = vtb + (size_t)jt * 2048;
        bf16x8 vf[4];
#pragma unroll
        for (int f = 0; f < 4; ++f)
            vf[f] = *(const bf16x8*)(vcur + f * 512 + l * 8);

        f32x16 s = {};
        __builtin_amdgcn_s_setprio(1);
        s = MFMA32(kf[0], qf[0], s);
        s = MFMA32(kf[1], qf[1], s);
        s = MFMA32(kf[2], qf[2], s);
        s = MFMA32(kf[3], qf[3], s);
        __builtin_amdgcn_s_setprio(0);

        kcur += 2048;
        if (jt + 1 < jt1) {
#pragma unroll
            for (int ks = 0; ks < 4; ++ks)
                kf[ks] = *(const bf16x8*)(kcur + ks * 512 + l * 8);
        }

        float t8[8];
#pragma unroll
        for (int q = 0; q < 8; ++q) t8[q] = fmaxf(s[2 * q], s[2 * q + 1]);
        float t4a = fmaxf(t8[0], t8[1]), t4b = fmaxf(t8[2], t8[3]);
        float t4c = fmaxf(t8[4], t8[5]), t4d = fmaxf(t8[6], t8[7]);
        float pmax = fmaxf(fmaxf(t4a, t4b), fmaxf(t4c, t4d));
        {
            unsigned int pu = __builtin_bit_cast(unsigned int, pmax), pv = pu;
            plswap(pu, pv, hi);
            pmax = fmaxf(__builtin_bit_cast(float, pu), __builtin_bit_cast(float, pv));
        }

        // defer-max (exp2 domain, THR=8 -> P <= 256)
        if (!__all(pmax - m <= 8.0f)) {
            float mn = fmaxf(m, pmax);
            float alpha = exp2_fast(m - mn);
            m = mn;
            lsum *= alpha;
#pragma unroll
            for (int r = 0; r < 16; ++r) { o0[r] *= alpha; o1[r] *= alpha; }
        }

        float p[16];
#pragma unroll
        for (int r = 0; r < 16; ++r) p[r] = exp2_fast(s[r] - m);
        float u8[8];
#pragma unroll
        for (int q = 0; q < 8; ++q) u8[q] = p[2 * q] + p[2 * q + 1];
        float u4a = u8[0] + u8[1], u4b = u8[2] + u8[3], u4c = u8[4] + u8[5], u4d = u8[6] + u8[7];
        float rsum = (u4a + u4b) + (u4c + u4d);
        {
            unsigned int pu = __builtin_bit_cast(unsigned int, rsum), pv = pu;
            plswap(pu, pv, hi);
            rsum = __builtin_bit_cast(float, pu) + __builtin_bit_cast(float, pv);
        }
        lsum += rsum;

        unsigned int W[8];
#pragma unroll
        for (int q = 0; q < 8; ++q) W[q] = cvtpk_bf16(p[2 * q], p[2 * q + 1]);
        plswap(W[0], W[2], hi); plswap(W[1], W[3], hi);
        plswap(W[4], W[6], hi); plswap(W[5], W[7], hi);
        u32x4 c0; c0[0] = W[0]; c0[1] = W[1]; c0[2] = W[2]; c0[3] = W[3];
        u32x4 c1; c1[0] = W[4]; c1[1] = W[5]; c1[2] = W[6]; c1[3] = W[7];
        bf16x8 pb0 = __builtin_bit_cast(bf16x8, c0);
        bf16x8 pb1 = __builtin_bit_cast(bf16x8, c1);

        __builtin_amdgcn_s_setprio(1);
        o0 = MFMA32(vf[0], pb0, o0);
        o0 = MFMA32(vf[1], pb1, o0);
        o1 = MFMA32(vf[2], pb0, o1);
        o1 = MFMA32(vf[3], pb1, o1);
        __builtin_amdgcn_s_setprio(0);
    }

    // ---- combine the two j-halves (partner wave = wid^2) ----
    mlbuf[0][wid][li] = m;
    mlbuf[1][wid][li] = lsum;
    __syncthreads();
    float mp = mlbuf[0][wid ^ 2][li];
    float lp = mlbuf[1][wid ^ 2][li];
    float mfin = fmaxf(m, mp);
    float aown = exp2_fast(m - mfin);
    float lfin = lsum * aown + lp * exp2_fast(mp - mfin);
#pragma unroll
    for (int r = 0; r < 16; ++r) { o0[r] *= aown; o1[r] *= aown; }

    if (jw == 1) {
        float* ob = &obuf[iw][0][0];
#pragma unroll
        for (int r = 0; r < 16; ++r) {
            int d0a = (r & 3) + 8 * (r >> 2) + 4 * hi;
            ob[d0a * 32 + li]        = o0[r];
            ob[(32 + d0a) * 32 + li] = o1[r];
        }
    }
    __syncthreads();
    if (jw == 0) {
        const float* ob = &obuf[iw][0][0];
#pragma unroll
        for (int r = 0; r < 16; ++r) {
            int d0a = (r & 3) + 8 * (r >> 2) + 4 * hi;
            o0[r] += ob[d0a * 32 + li];
            o1[r] += ob[(32 + d0a) * 32 + li];
        }

        float inv = 1.0f / lfin;
        unsigned short* tw = &tb[iw][0];
#pragma unroll
        for (int dt = 0; dt < 2; ++dt) {
            const f32x16& oo = dt ? o1 : o0;
#pragma unroll
            for (int q = 0; q < 8; ++q) {
                int r = 2 * q;
                int d0 = dt * 32 + (r & 3) + 8 * (r >> 2) + 4 * hi;
                unsigned int wpk = cvtpk_bf16(oo[r] * inv, oo[r + 1] * inv);
                *(unsigned int*)((char*)tw + li * 144 + d0 * 2) = wpk;
            }
        }
        // tb is wave-private (iw-indexed); in-wave ds ordering is program-order.
        // packed ao write: row n = i0+li, cols c = h*64 + hi*32 + k*8 + e
        //   rt = i0>>5, kt = 2h+hi, sub = li>>4, l15 = li&15, l4 = k
        int rt = i0 >> 5;
        unsigned short* pao = ao + (size_t)b * NN * HID
            + (size_t)(((rt * 16 + 2 * h + hi) * 2 + (li >> 4))) * 512 + (li & 15) * 32;
#pragma unroll
        for (int k = 0; k < 4; ++k) {
            bf16x8 v = *(const bf16x8*)((const char*)tw + li * 144 + (hi * 32 + k * 8) * 2);
            *(bf16x8*)(pao + k * 8) = v;
        }
    }
}

// ---------- stage 3: out = w_out @ att + b_out (packed operands) ----------
__global__ __launch_bounds__(256) void k_proj(
    const unsigned short* __restrict__ wo,  // packed [8rt][16kt]
    const unsigned short* __restrict__ ao,  // packed [4][64rt][16kt]
    const float* __restrict__ bout, float* __restrict__ out)
{
    int ob = blockIdx.x, nb = blockIdx.y, b = blockIdx.z;
    int wid = threadIdx.x >> 6;
    int l = threadIdx.x & 63, l15 = l & 15, l4 = l >> 4;
    int wr = wid >> 1, wc = wid & 1;
    int o0 = ob * 64 + wr * 32, n0 = nb * 64 + wc * 32;
    int lane_off = l15 * 32 + l4 * 8;
    int rt_a = ob * 2 + wr;          // wo rows o
    int rt_b = nb * 2 + wc;          // ao rows n
    const unsigned short* aob = ao + (size_t)b * NN * HID;
    f32x4 acc[2][2] = {};
#pragma unroll
    for (int kt = 0; kt < 16; ++kt) {
        const unsigned short* at = wo + (size_t)((rt_a * 16 + kt) * 2) * 512 + lane_off;
        const unsigned short* bt = aob + (size_t)((rt_b * 16 + kt) * 2) * 512 + lane_off;
        bf16x8 a0 = *(const bf16x8*)(at);
        bf16x8 a1 = *(const bf16x8*)(at + 512);
        bf16x8 b0 = *(const bf16x8*)(bt);
        bf16x8 b1 = *(const bf16x8*)(bt + 512);
        acc[0][0] = MFMA16(a0, b0, acc[0][0]);
        acc[0][1] = MFMA16(a0, b1, acc[0][1]);
        acc[1][0] = MFMA16(a1, b0, acc[1][0]);
        acc[1][1] = MFMA16(a1, b1, acc[1][1]);
    }
#pragma unroll
    for (int fm = 0; fm < 2; ++fm)
#pragma unroll
        for (int fn = 0; fn < 2; ++fn)
#pragma unroll
            for (int r = 0; r < 4; ++r) {
                int o = o0 + fm * 16 + l4 * 4 + r;
                int n = n0 + fn * 16 + l15;
                out[((size_t)(b * DIMC + o)) * NN + n] = acc[fm][fn][r] + bout[o];
            }
}

// ---------- launch ----------
extern "C" void kernel_launch(void* const* d_in, const int* in_sizes, int n_in,
                              void* d_out, int out_size, void* d_ws, size_t ws_size,
                              hipStream_t stream)
{
    const float* x    = (const float*)d_in[0];
    const float* wqkv = (const float*)d_in[1];
    const float* wout = (const float*)d_in[2];
    const float* bout = (const float*)d_in[3];
    float* out = (float*)d_out;
    char* ws = (char*)d_ws;

    unsigned short* xt  = (unsigned short*)(ws + OFF_XT);
    unsigned short* wqb = (unsigned short*)(ws + OFF_WQ);
    unsigned short* wob = (unsigned short*)(ws + OFF_WO);
    unsigned short* qT  = (unsigned short*)(ws + OFF_Q);
    unsigned short* kTt = (unsigned short*)(ws + OFF_K);
    unsigned short* vTt = (unsigned short*)(ws + OFF_V);
    unsigned short* ao  = (unsigned short*)(ws + OFF_AO);

    hipLaunchKernelGGL(k_prep, dim3(32, 4, 4), dim3(256), 0, stream, x, wqkv, wout, xt, wqb, wob);
    hipLaunchKernelGGL(k_qkv, dim3(24, 32, 4), dim3(256), 0, stream, wqb, xt, qT, kTt, vTt);
    hipLaunchKernelGGL(k_attn5, dim3(1024), dim3(256), 0, stream, qT, kTt, vTt, ao);
    hipLaunchKernelGGL(k_proj, dim3(4, 32, 4), dim3(256), 0, stream, wob, ao, bout, out);
}

// Round 10
// 156.248 us; speedup vs baseline: 1.6155x; 1.0205x over previous
//
#include <hip/hip_runtime.h>
#include <hip/hip_bf16.h>

// ---------- types ----------
using f32x4  = __attribute__((ext_vector_type(4))) float;
using f32x16 = __attribute__((ext_vector_type(16))) float;
using bf16x8 = __attribute__((ext_vector_type(8))) short;   // 8 bf16 (4 VGPRs)
using u32x2  = __attribute__((ext_vector_type(2))) unsigned int;
using u32x4  = __attribute__((ext_vector_type(4))) unsigned int;

#define MFMA16(a, b, c) __builtin_amdgcn_mfma_f32_16x16x32_bf16((a), (b), (c), 0, 0, 0)
#define MFMA32(a, b, c) __builtin_amdgcn_mfma_f32_32x32x16_bf16((a), (b), (c), 0, 0, 0)

static __device__ __forceinline__ unsigned short f2bf(float x) {
    unsigned int u = __builtin_bit_cast(unsigned int, x);
    unsigned int r = (u + 0x7fffu + ((u >> 16) & 1u)) >> 16;
    return (unsigned short)r;
}

static __device__ __forceinline__ unsigned int cvtpk_bf16(float a, float b) {
    unsigned int r;
    asm("v_cvt_pk_bf16_f32 %0, %1, %2" : "=v"(r) : "v"(a), "v"(b));
    return r;
}

static __device__ __forceinline__ float exp2_fast(float x) {
#if __has_builtin(__builtin_amdgcn_exp2f)
    return __builtin_amdgcn_exp2f(x);
#else
    return __expf(x * 0.69314718056f);
#endif
}

static __device__ __forceinline__ void plswap(unsigned int& x, unsigned int& y, int hi) {
#if __has_builtin(__builtin_amdgcn_permlane32_swap)
    u32x2 r = __builtin_amdgcn_permlane32_swap(x, y, false, false);
    x = r[0]; y = r[1];
#else
    unsigned int xs = (unsigned int)__shfl_xor((int)x, 32);
    unsigned int ys = (unsigned int)__shfl_xor((int)y, 32);
    unsigned int nx = hi ? ys : x;
    unsigned int ny = hi ? y  : xs;
    x = nx; y = ny;
#endif
}

// ---------- geometry ----------
#define NB 4
#define DIMC 256
#define NN 2048
#define NH 8
#define DH 64
#define HID 512

// q scale: dhead^-0.5 * log2(e) so softmax runs in exp2 domain
#define QSCALE 0.18033688f

// Fragtile packed operand layout (16x16x32 MFMA fragments):
//   (row, col) -> [rt=row/32][kt=col/32][sub=(row&31)>>4][l15=row&15][l4=(col>>3)&3][e=col&7]
// Attention tile layout (32x32x16 MFMA fragments), per 32-tile of seq x 64 of d/j:
//   Q/K: [ks=k>>4][hi=(k>>3)&1][li=row&31][e=k&7]   (2048 elem / tile)
//   V:   [dt*2+js][hi=(j>>3)&1][li=d&31][e=j&7]

// workspace offsets (bytes)
#define OFF_XT  0u            // [4] packed x^T  (rows n, K=256)
#define OFF_WQ  4194304u      // packed w_qkv (rows o=1536, K=256)
#define OFF_WO  4980736u      // packed w_out (rows o=256, K=512)
#define OFF_Q   5242880u      // [32 bh][64 it][2048] bf16 PACKED Q tiles (q * QSCALE)
#define OFF_K   13631488u     // [32 bh][64 jt][2048] bf16 PACKED K tiles
#define OFF_V   22020096u     // [32 bh][64 jt][2048] bf16 PACKED V^T tiles
#define OFF_AO  30408704u     // [4] packed attn-out (rows n, K=hid=512)

// ---------- stage 0: x transpose->packed bf16 + weight convert->packed (fused) ----------
__global__ __launch_bounds__(256) void k_prep(
    const float* __restrict__ x, const float* __restrict__ wqkv,
    const float* __restrict__ wout,
    unsigned short* __restrict__ xt, unsigned short* __restrict__ wq_b,
    unsigned short* __restrict__ wo_b)
{
    int wg = blockIdx.x + 32 * blockIdx.y + 128 * blockIdx.z;
    int tid = wg * 256 + threadIdx.x;
    if (tid < 98304) {
        // wqkv [1536][256]: 64 float4 per row
        int o = tid >> 6, c4 = (tid & 63) * 4;
        float4 v = ((const float4*)wqkv)[tid];
        u32x2 pk; pk[0] = cvtpk_bf16(v.x, v.y); pk[1] = cvtpk_bf16(v.z, v.w);
        int rt = o >> 5, rr = o & 31, sub = rr >> 4, l15f = rr & 15;
        int kt = c4 >> 5, l4f = (c4 >> 3) & 3, e = c4 & 7;
        size_t off = (size_t)(((rt * 8 + kt) * 2 + sub)) * 512 + l15f * 32 + l4f * 8 + e;
        *(u32x2*)(wq_b + off) = pk;
    } else {
        // wout [256][512]: 128 float4 per row
        int t2 = tid - 98304;
        int o = t2 >> 7, c4 = (t2 & 127) * 4;
        float4 v = ((const float4*)wout)[t2];
        u32x2 pk; pk[0] = cvtpk_bf16(v.x, v.y); pk[1] = cvtpk_bf16(v.z, v.w);
        int rt = o >> 5, rr = o & 31, sub = rr >> 4, l15f = rr & 15;
        int kt = c4 >> 5, l4f = (c4 >> 3) & 3, e = c4 & 7;
        size_t off = (size_t)(((rt * 16 + kt) * 2 + sub)) * 512 + l15f * 32 + l4f * 8 + e;
        *(u32x2*)(wo_b + off) = pk;
    }

    __shared__ unsigned short tile[64][65];
    int nb = blockIdx.x, cb = blockIdx.y, b = blockIdx.z;
    int t = threadIdx.x;
    int tn = t & 63, tg = t >> 6;
    const float* xp = x + ((size_t)(b * DIMC + cb * 64)) * NN + nb * 64;
#pragma unroll
    for (int it = 0; it < 16; ++it) {
        int c = tg * 16 + it;
        tile[c][tn] = f2bf(xp[(size_t)c * NN + tn]);
    }
    __syncthreads();
    // packed write: row R = nb*64 + n, col C = cb*64 + tn
    unsigned short* xb = xt + (size_t)b * NN * DIMC;
    int C = cb * 64 + tn;
    int kt = C >> 5, l4f = (C >> 3) & 3, e = C & 7;
#pragma unroll
    for (int it = 0; it < 16; ++it) {
        int n = tg * 16 + it;
        int R = nb * 64 + n;
        int rt = R >> 5, rr = R & 31, sub = rr >> 4, l15f = rr & 15;
        xb[(size_t)(((rt * 8 + kt) * 2 + sub)) * 512 + l15f * 32 + l4f * 8 + e] = tile[tn][n];
    }
}

// ---------- stage 1: qkv = w_qkv @ x (packed in, packed out, vectorized stores) ----------
// bx 0..7: q (D[o][n], A=wq) -> packed Q tiles, scaled
// bx 8..15: k (D[o][n], A=wq) -> packed K tiles
// bx 16..23: v (D[n][o], A=xt) -> packed V^T tiles
// All epilogue stores are 8B (4 consecutive e-slots per (fm,fn)).
__global__ __launch_bounds__(256) void k_qkv(
    const unsigned short* __restrict__ wq,  // packed [48rt][8kt]
    const unsigned short* __restrict__ xt,  // packed [4][64rt][8kt]
    unsigned short* __restrict__ qTt, unsigned short* __restrict__ kTt,
    unsigned short* __restrict__ vTt)
{
    int bx = blockIdx.x;          // o-tile 0..23
    int nb = blockIdx.y;          // n-tile 0..31
    int b  = blockIdx.z;
    int wid = threadIdx.x >> 6;
    int l = threadIdx.x & 63, l15 = l & 15, l4 = l >> 4;
    int wr = wid >> 1, wc = wid & 1;
    int lane_off = l15 * 32 + l4 * 8;
    const unsigned short* xb = xt + (size_t)b * NN * DIMC;
    bool isv = (bx >= 16);

    int rt_a = isv ? (nb * 2 + wr) : (bx * 2 + wr);
    int rt_b = isv ? (bx * 2 + wc) : (nb * 2 + wc);
    const unsigned short* abase = isv ? xb : wq;
    const unsigned short* bbase = isv ? wq : xb;

    f32x4 acc[2][2] = {};
#pragma unroll
    for (int kt = 0; kt < 8; ++kt) {
        const unsigned short* at = abase + (size_t)((rt_a * 8 + kt) * 2) * 512 + lane_off;
        const unsigned short* bt = bbase + (size_t)((rt_b * 8 + kt) * 2) * 512 + lane_off;
        bf16x8 a0 = *(const bf16x8*)(at);
        bf16x8 a1 = *(const bf16x8*)(at + 512);
        bf16x8 b0 = *(const bf16x8*)(bt);
        bf16x8 b1 = *(const bf16x8*)(bt + 512);
        acc[0][0] = MFMA16(a0, b0, acc[0][0]);
        acc[0][1] = MFMA16(a0, b1, acc[0][1]);
        acc[1][0] = MFMA16(a1, b0, acc[1][0]);
        acc[1][1] = MFMA16(a1, b1, acc[1][1]);
    }

    int hi2 = (l4 >> 1), e0 = (l4 & 1) * 4;
    if (!isv) {
        // rows=o: d = wr*32+fm*16+l4*4+r ; cols=n: j/i = wc*32+fn*16+l15 (+nb*64)
        int h = (bx < 8) ? bx : (bx - 8);
        unsigned short* dst = (bx < 8) ? qTt : kTt;
        float s = (bx < 8) ? QSCALE : 1.0f;
        size_t hbase = ((size_t)(b * NH + h) * 64 + (nb * 2 + wc)) * 2048;
#pragma unroll
        for (int fm = 0; fm < 2; ++fm)
#pragma unroll
            for (int fn = 0; fn < 2; ++fn) {
                int li = fn * 16 + l15;
                u32x2 pk;
                pk[0] = cvtpk_bf16(acc[fm][fn][0] * s, acc[fm][fn][1] * s);
                pk[1] = cvtpk_bf16(acc[fm][fn][2] * s, acc[fm][fn][3] * s);
                *(u32x2*)(dst + hbase + (wr * 2 + fm) * 512 + hi2 * 256 + li * 8 + e0) = pk;
            }
    } else {
        // rows=n: j = wr*32+fm*16+l4*4+r (+nb*64); cols=o: d = wc*32+fn*16+l15
        int h = bx - 16;
        size_t hbase = ((size_t)(b * NH + h) * 64 + (nb * 2 + wr)) * 2048;
#pragma unroll
        for (int fm = 0; fm < 2; ++fm)
#pragma unroll
            for (int fn = 0; fn < 2; ++fn) {
                int li = fn * 16 + l15;
                u32x2 pk;
                pk[0] = cvtpk_bf16(acc[fm][fn][0], acc[fm][fn][1]);
                pk[1] = cvtpk_bf16(acc[fm][fn][2], acc[fm][fn][3]);
                *(u32x2*)(vTt + hbase + (wc * 2 + fm) * 512 + hi2 * 256 + li * 8 + e0) = pk;
            }
    }
}

// ---------- stage 2: flash attention, swapped 32x32x16, j-split x2, fully packed ----------
// 1024 blocks x 4 waves. wid&1 = i-subtile (32 rows), wid>>1 = KV half (1024 each).
// Q/K/V loads all coalesced (base + f*512 + l*8); ao written fragtile-packed for k_proj.
__global__ __launch_bounds__(256) void k_attn5(
    const unsigned short* __restrict__ qTt, const unsigned short* __restrict__ kTt,
    const unsigned short* __restrict__ vTt, unsigned short* __restrict__ ao)
{
    __shared__ float obuf[2][64][32];        // 16 KB: j-half-1 deposits O^T
    __shared__ float mlbuf[2][4][32];        // m, l per wave
    __shared__ unsigned short tb[2][32 * 72];// epilogue transpose (waves jw==0)

    int wg = blockIdx.x;            // 0..1023
    int xcd = wg & 7;
    int idx = wg >> 3;              // 0..127
    int bh  = xcd * 4 + (idx & 3);  // 4 bh per XCD -> K/V L2-resident
    int ib  = idx >> 2;             // 0..31
    int b = bh >> 3, h = bh & 7;
    int wid = threadIdx.x >> 6;     // 0..3
    int iw = wid & 1, jw = wid >> 1;
    int l = threadIdx.x & 63, li = l & 31, hi = l >> 5;
    int i0 = ib * 64 + iw * 32;

    const unsigned short* qtile = qTt + ((size_t)bh * 64 + (ib * 2 + iw)) * 2048;
    const unsigned short* ktb = kTt + (size_t)bh * 64 * 2048;
    const unsigned short* vtb = vTt + (size_t)bh * 64 * 2048;

    bf16x8 qf[4];
#pragma unroll
    for (int ks = 0; ks < 4; ++ks)
        qf[ks] = *(const bf16x8*)(qtile + ks * 512 + l * 8);

    f32x16 o0 = {}, o1 = {};
    float m = -1e30f, lsum = 0.f;

    const int jt0 = jw * 32, jt1 = jt0 + 32;   // 32 j-tiles of 32 = 1024 KV positions

    const unsigned short* kcur = ktb + (size_t)jt0 * 2048;
    bf16x8 kf[4];
#pragma unroll
    for (int ks = 0; ks < 4; ++ks)
        kf[ks] = *(const bf16x8*)(kcur + ks * 512 + l * 8);

    for (int jt = jt0; jt < jt1; ++jt) {
        const unsigned short* vcur = vtb + (size_t)jt * 2048;
        bf16x8 vf[4];
#pragma unroll
        for (int f = 0; f < 4; ++f)
            vf[f] = *(const bf16x8*)(vcur + f * 512 + l * 8);

        f32x16 s = {};
        __builtin_amdgcn_s_setprio(1);
        s = MFMA32(kf[0], qf[0], s);
        s = MFMA32(kf[1], qf[1], s);
        s = MFMA32(kf[2], qf[2], s);
        s = MFMA32(kf[3], qf[3], s);
        __builtin_amdgcn_s_setprio(0);

        kcur += 2048;
        if (jt + 1 < jt1) {
#pragma unroll
            for (int ks = 0; ks < 4; ++ks)
                kf[ks] = *(const bf16x8*)(kcur + ks * 512 + l * 8);
        }

        float t8[8];
#pragma unroll
        for (int q = 0; q < 8; ++q) t8[q] = fmaxf(s[2 * q], s[2 * q + 1]);
        float t4a = fmaxf(t8[0], t8[1]), t4b = fmaxf(t8[2], t8[3]);
        float t4c = fmaxf(t8[4], t8[5]), t4d = fmaxf(t8[6], t8[7]);
        float pmax = fmaxf(fmaxf(t4a, t4b), fmaxf(t4c, t4d));
        {
            unsigned int pu = __builtin_bit_cast(unsigned int, pmax), pv = pu;
            plswap(pu, pv, hi);
            pmax = fmaxf(__builtin_bit_cast(float, pu), __builtin_bit_cast(float, pv));
        }

        // defer-max (exp2 domain, THR=8 -> P <= 256)
        if (!__all(pmax - m <= 8.0f)) {
            float mn = fmaxf(m, pmax);
            float alpha = exp2_fast(m - mn);
            m = mn;
            lsum *= alpha;
#pragma unroll
            for (int r = 0; r < 16; ++r) { o0[r] *= alpha; o1[r] *= alpha; }
        }

        float p[16];
#pragma unroll
        for (int r = 0; r < 16; ++r) p[r] = exp2_fast(s[r] - m);
        float u8[8];
#pragma unroll
        for (int q = 0; q < 8; ++q) u8[q] = p[2 * q] + p[2 * q + 1];
        float u4a = u8[0] + u8[1], u4b = u8[2] + u8[3], u4c = u8[4] + u8[5], u4d = u8[6] + u8[7];
        float rsum = (u4a + u4b) + (u4c + u4d);
        {
            unsigned int pu = __builtin_bit_cast(unsigned int, rsum), pv = pu;
            plswap(pu, pv, hi);
            rsum = __builtin_bit_cast(float, pu) + __builtin_bit_cast(float, pv);
        }
        lsum += rsum;

        unsigned int W[8];
#pragma unroll
        for (int q = 0; q < 8; ++q) W[q] = cvtpk_bf16(p[2 * q], p[2 * q + 1]);
        plswap(W[0], W[2], hi); plswap(W[1], W[3], hi);
        plswap(W[4], W[6], hi); plswap(W[5], W[7], hi);
        u32x4 c0; c0[0] = W[0]; c0[1] = W[1]; c0[2] = W[2]; c0[3] = W[3];
        u32x4 c1; c1[0] = W[4]; c1[1] = W[5]; c1[2] = W[6]; c1[3] = W[7];
        bf16x8 pb0 = __builtin_bit_cast(bf16x8, c0);
        bf16x8 pb1 = __builtin_bit_cast(bf16x8, c1);

        __builtin_amdgcn_s_setprio(1);
        o0 = MFMA32(vf[0], pb0, o0);
        o0 = MFMA32(vf[1], pb1, o0);
        o1 = MFMA32(vf[2], pb0, o1);
        o1 = MFMA32(vf[3], pb1, o1);
        __builtin_amdgcn_s_setprio(0);
    }

    // ---- combine the two j-halves (partner wave = wid^2) ----
    mlbuf[0][wid][li] = m;
    mlbuf[1][wid][li] = lsum;
    __syncthreads();
    float mp = mlbuf[0][wid ^ 2][li];
    float lp = mlbuf[1][wid ^ 2][li];
    float mfin = fmaxf(m, mp);
    float aown = exp2_fast(m - mfin);
    float lfin = lsum * aown + lp * exp2_fast(mp - mfin);
#pragma unroll
    for (int r = 0; r < 16; ++r) { o0[r] *= aown; o1[r] *= aown; }

    if (jw == 1) {
        float* ob = &obuf[iw][0][0];
#pragma unroll
        for (int r = 0; r < 16; ++r) {
            int d0a = (r & 3) + 8 * (r >> 2) + 4 * hi;
            ob[d0a * 32 + li]        = o0[r];
            ob[(32 + d0a) * 32 + li] = o1[r];
        }
    }
    __syncthreads();
    if (jw == 0) {
        const float* ob = &obuf[iw][0][0];
#pragma unroll
        for (int r = 0; r < 16; ++r) {
            int d0a = (r & 3) + 8 * (r >> 2) + 4 * hi;
            o0[r] += ob[d0a * 32 + li];
            o1[r] += ob[(32 + d0a) * 32 + li];
        }

        float inv = 1.0f / lfin;
        unsigned short* tw = &tb[iw][0];
#pragma unroll
        for (int dt = 0; dt < 2; ++dt) {
            const f32x16& oo = dt ? o1 : o0;
#pragma unroll
            for (int q = 0; q < 8; ++q) {
                int r = 2 * q;
                int d0 = dt * 32 + (r & 3) + 8 * (r >> 2) + 4 * hi;
                unsigned int wpk = cvtpk_bf16(oo[r] * inv, oo[r + 1] * inv);
                *(unsigned int*)((char*)tw + li * 144 + d0 * 2) = wpk;
            }
        }
        // tb is wave-private (iw-indexed); in-wave ds ordering is program-order.
        // packed ao write: row n = i0+li, cols c = h*64 + hi*32 + k*8 + e
        int rt = i0 >> 5;
        unsigned short* pao = ao + (size_t)b * NN * HID
            + (size_t)(((rt * 16 + 2 * h + hi) * 2 + (li >> 4))) * 512 + (li & 15) * 32;
#pragma unroll
        for (int k = 0; k < 4; ++k) {
            bf16x8 v = *(const bf16x8*)((const char*)tw + li * 144 + (hi * 32 + k * 8) * 2);
            *(bf16x8*)(pao + k * 8) = v;
        }
    }
}

// ---------- stage 3: out = w_out @ att + b_out (packed operands) ----------
__global__ __launch_bounds__(256) void k_proj(
    const unsigned short* __restrict__ wo,  // packed [8rt][16kt]
    const unsigned short* __restrict__ ao,  // packed [4][64rt][16kt]
    const float* __restrict__ bout, float* __restrict__ out)
{
    int ob = blockIdx.x, nb = blockIdx.y, b = blockIdx.z;
    int wid = threadIdx.x >> 6;
    int l = threadIdx.x & 63, l15 = l & 15, l4 = l >> 4;
    int wr = wid >> 1, wc = wid & 1;
    int o0 = ob * 64 + wr * 32, n0 = nb * 64 + wc * 32;
    int lane_off = l15 * 32 + l4 * 8;
    int rt_a = ob * 2 + wr;          // wo rows o
    int rt_b = nb * 2 + wc;          // ao rows n
    const unsigned short* aob = ao + (size_t)b * NN * HID;
    f32x4 acc[2][2] = {};
#pragma unroll
    for (int kt = 0; kt < 16; ++kt) {
        const unsigned short* at = wo + (size_t)((rt_a * 16 + kt) * 2) * 512 + lane_off;
        const unsigned short* bt = aob + (size_t)((rt_b * 16 + kt) * 2) * 512 + lane_off;
        bf16x8 a0 = *(const bf16x8*)(at);
        bf16x8 a1 = *(const bf16x8*)(at + 512);
        bf16x8 b0 = *(const bf16x8*)(bt);
        bf16x8 b1 = *(const bf16x8*)(bt + 512);
        acc[0][0] = MFMA16(a0, b0, acc[0][0]);
        acc[0][1] = MFMA16(a0, b1, acc[0][1]);
        acc[1][0] = MFMA16(a1, b0, acc[1][0]);
        acc[1][1] = MFMA16(a1, b1, acc[1][1]);
    }
#pragma unroll
    for (int fm = 0; fm < 2; ++fm)
#pragma unroll
        for (int fn = 0; fn < 2; ++fn)
#pragma unroll
            for (int r = 0; r < 4; ++r) {
                int o = o0 + fm * 16 + l4 * 4 + r;
                int n = n0 + fn * 16 + l15;
                out[((size_t)(b * DIMC + o)) * NN + n] = acc[fm][fn][r] + bout[o];
            }
}

// ---------- launch ----------
extern "C" void kernel_launch(void* const* d_in, const int* in_sizes, int n_in,
                              void* d_out, int out_size, void* d_ws, size_t ws_size,
                              hipStream_t stream)
{
    const float* x    = (const float*)d_in[0];
    const float* wqkv = (const float*)d_in[1];
    const float* wout = (const float*)d_in[2];
    const float* bout = (const float*)d_in[3];
    float* out = (float*)d_out;
    char* ws = (char*)d_ws;

    unsigned short* xt  = (unsigned short*)(ws + OFF_XT);
    unsigned short* wqb = (unsigned short*)(ws + OFF_WQ);
    unsigned short* wob = (unsigned short*)(ws + OFF_WO);
    unsigned short* qTt = (unsigned short*)(ws + OFF_Q);
    unsigned short* kTt = (unsigned short*)(ws + OFF_K);
    unsigned short* vTt = (unsigned short*)(ws + OFF_V);
    unsigned short* ao  = (unsigned short*)(ws + OFF_AO);

    hipLaunchKernelGGL(k_prep, dim3(32, 4, 4), dim3(256), 0, stream, x, wqkv, wout, xt, wqb, wob);
    hipLaunchKernelGGL(k_qkv, dim3(24, 32, 4), dim3(256), 0, stream, wqb, xt, qTt, kTt, vTt);
    hipLaunchKernelGGL(k_attn5, dim3(1024), dim3(256), 0, stream, qTt, kTt, vTt, ao);
    hipLaunchKernelGGL(k_proj, dim3(4, 32, 4), dim3(256), 0, stream, wob, ao, bout, out);
}